// Round 3
// baseline (571.439 us; speedup 1.0000x reference)
//
#include <hip/hip_runtime.h>

#define IN_F 8192
#define OUT_F 8192

typedef float v4f __attribute__((ext_vector_type(4)));

// One 64-lane wave per output row. No LDS, no __syncthreads.
// Phase 1: stream the states row (32 x float4 per lane), reduce wsum/dot via
//          shfl_xor butterfly (every lane ends with the full sums -> spike).
// Phase 2: stream trace row: load, update, clamped nontemporal store.
// x (32 KB) is re-read in phase 2 and served by L1/L2.
__global__ __launch_bounds__(256) void snn_wave_kernel(
    const float* __restrict__ x,       // [IN_F]
    const float* __restrict__ states,  // [OUT_F, IN_F]
    const float* __restrict__ mp,      // [OUT_F]
    const float* __restrict__ thr,     // [OUT_F]
    const float* __restrict__ trace,   // [OUT_F, IN_F]
    float* __restrict__ out)           // spikes[O] | v[O] | thr[O] | trace[O*I]
{
    const int lane = threadIdx.x & 63;
    const int o    = (blockIdx.x << 2) + (threadIdx.x >> 6);  // row = global wave id

    const float mp_o  = mp[o];
    const float thr_o = thr[o];

    const v4f* __restrict__ x4 = (const v4f*)x;
    const v4f* __restrict__ s4 = (const v4f*)(states + (size_t)o * IN_F);

    // 2048 float4 per row / 64 lanes = 32 float4 per lane
    float wsum = 0.0f, dot = 0.0f;
#pragma unroll
    for (int k = 0; k < 32; ++k) {
        const int idx = lane + (k << 6);
        const v4f sv = __builtin_nontemporal_load(&s4[idx]);  // streaming
        const v4f xv = x4[idx];                               // cache-resident
        const float w0 = (sv[0] > 50.0f) ? 1.0f : 0.0f;
        const float w1 = (sv[1] > 50.0f) ? 1.0f : 0.0f;
        const float w2 = (sv[2] > 50.0f) ? 1.0f : 0.0f;
        const float w3 = (sv[3] > 50.0f) ? 1.0f : 0.0f;
        wsum += (w0 + w1) + (w2 + w3);
        dot  += (w0 * xv[0] + w1 * xv[1]) + (w2 * xv[2] + w3 * xv[3]);
    }

    // butterfly: all 64 lanes end with the full-row sums (exact integers in f32)
#pragma unroll
    for (int off = 32; off > 0; off >>= 1) {
        wsum += __shfl_xor(wsum, off);
        dot  += __shfl_xor(dot,  off);
    }

    const float conn    = fmaxf(wsum, 5.0f);
    const float v       = mp_o * 0.85f + dot * (15.0f / sqrtf(conn));
    const float spike   = (v >= thr_o) ? 1.0f : 0.0f;

    if (lane == 0) {
        out[o]             = spike;
        out[OUT_F + o]     = v * (1.0f - spike) * 0.1f;
        out[2 * OUT_F + o] = fminf(fmaxf(thr_o + (spike - 0.1f) * 0.1f, 2.0f), 15.0f);
    }

    const v4f* __restrict__ tr4 = (const v4f*)(trace + (size_t)o * IN_F);
    v4f* __restrict__ ot4       = (v4f*)(out + 3 * OUT_F + (size_t)o * IN_F);
#pragma unroll 8
    for (int k = 0; k < 32; ++k) {
        const int idx = lane + (k << 6);
        const v4f tv = __builtin_nontemporal_load(&tr4[idx]);  // L3-hot
        const v4f xv = x4[idx];                                // L1-hot
        v4f r;
        r[0] = fminf(fmaxf(tv[0] * 0.9f + spike * xv[0], 0.0f), 5.0f);
        r[1] = fminf(fmaxf(tv[1] * 0.9f + spike * xv[1], 0.0f), 5.0f);
        r[2] = fminf(fmaxf(tv[2] * 0.9f + spike * xv[2], 0.0f), 5.0f);
        r[3] = fminf(fmaxf(tv[3] * 0.9f + spike * xv[3], 0.0f), 5.0f);
        __builtin_nontemporal_store(r, &ot4[idx]);
    }
}

extern "C" void kernel_launch(void* const* d_in, const int* in_sizes, int n_in,
                              void* d_out, int out_size, void* d_ws, size_t ws_size,
                              hipStream_t stream) {
    const float* x      = (const float*)d_in[0];  // spike_input [8192]
    const float* states = (const float*)d_in[1];  // synapse_states [8192*8192]
    const float* mp     = (const float*)d_in[2];  // membrane_potential [8192]
    const float* thr    = (const float*)d_in[3];  // adaptive_threshold [8192]
    const float* trace  = (const float*)d_in[4];  // eligibility_trace [8192*8192]
    float* out = (float*)d_out;

    // 8192 rows, 1 wave (64 lanes) per row, 4 waves per 256-thread block
    snn_wave_kernel<<<OUT_F / 4, 256, 0, stream>>>(x, states, mp, thr, trace, out);
}